// Round 1
// baseline (10130.696 us; speedup 1.0000x reference)
//
#include <hip/hip_runtime.h>
#include <stdint.h>

// ---------------------------------------------------------------------------
// PromptSaturationDetector: 4-layer stacked LSTM -> fanout/LeakyReLU/fanin ->
// LSTM -> head(sigmoid) as a single persistent producer/consumer pipeline.
//
// Roles inside k_pipe (48 blocks x 256 threads, all co-resident):
//   blocks 0..19 : REC  (5 layers x 4 blocks) - serial recurrence, Whh as
//                  register-resident MFMA B-frags, h exchange via agent-scope
//                  atomics each step.
//   blocks 20..47: STREAM (XG0..XG4, FO, FI x 4 blocks) - chunked (8-step)
//                  bf16 MFMA GEMMs feeding the REC stages through rings in ws.
// ---------------------------------------------------------------------------

#define B_ 16
#define T_ 2048
#define H_ 256
#define NG 1024
#define F_ 1024
#define CHUNK 8
#define NCH 256            // T_/CHUNK
#define WH 128             // h ring slots (steps)
#define WXG 128            // xg ring slots (steps)
#define WCH 16             // chunk ring slots (= 128 steps)
#define PREC 4             // blocks per recurrent layer
#define GS 4               // blocks per stream stage
#define NRECB (5*PREC)     // 20
#define NBLK (NRECB + 7*GS)// 48
#define APITCH 264         // LDS row pitch in bf16 elems (bank-safe, 16B mult)
#define WELEM 262144       // 1024*256

typedef __attribute__((ext_vector_type(4))) float f32x4;
typedef __attribute__((ext_vector_type(8))) short bf16x8;

// ---- workspace layout (bytes) ----
#define OFF_XG   0ul
#define SZ_XG    (5ul*WXG*NG*B_*4ul)           // [5][128][1024][16] f32
#define OFF_H    (OFF_XG + SZ_XG)
#define SZ_H     (5ul*WH*B_*H_*2ul)            // [5][128][16][256] bf16
#define OFF_FO   (OFF_H + SZ_H)
#define SZ_FO    ((unsigned long)WCH*128ul*F_*2ul)   // [16][128][1024] bf16
#define OFF_FI   (OFF_FO + SZ_FO)
#define SZ_FI    ((unsigned long)WCH*128ul*H_*2ul)   // [16][128][256] bf16
#define OFF_WBF  (OFF_FI + SZ_FI)
#define SZ_WBF   (7ul*WELEM*2ul)               // wih0..3, wih4, foW, fiW (bf16)
#define OFF_H4   (OFF_WBF + SZ_WBF)
#define SZ_H4    ((unsigned long)B_*H_*4ul)
#define OFF_FLAG (OFF_H4 + SZ_H4 + 256ul)

// flag word indices
#define FL_ARRIVE 0     // [5]  rec arrival counters (target PREC*(t+1))
#define FL_XGF    8     // [5][16] xg chunk-ready flags (value tc+1)
#define FL_FOF    96    // [16]
#define FL_FIF    112   // [16]
#define FL_XGP    128   // [5][4] per-pool-block progress (chunks done)
#define FL_FOP    152   // [4]
#define FL_FIP    156   // [4]
#define FL_N      160

__device__ __forceinline__ unsigned short f2bf(float f) {
  unsigned int u = __float_as_uint(f);
  u = u + 0x7fffu + ((u >> 16) & 1u);          // round-to-nearest-even
  return (unsigned short)(u >> 16);
}
__device__ __forceinline__ float sigm_f(float x) { return 1.0f / (1.0f + __expf(-x)); }
__device__ __forceinline__ float tanh_f(float x) {
  float e = __expf(-2.0f * fabsf(x));
  float r = (1.0f - e) / (1.0f + e);
  return x >= 0.0f ? r : -r;
}
// spin until *p >= tgt (relaxed polls, one acquire at the end); bounded so a
// protocol bug shows as wrong output instead of a hang.
__device__ __forceinline__ void spin_ge(unsigned int* p, unsigned int tgt) {
  int n = 0;
  while (__hip_atomic_load(p, __ATOMIC_RELAXED, __HIP_MEMORY_SCOPE_AGENT) < tgt) {
    __builtin_amdgcn_s_sleep(1);
    if (++n > 50000000) break;
  }
  (void)__hip_atomic_load(p, __ATOMIC_ACQUIRE, __HIP_MEMORY_SCOPE_AGENT);
}

// ---------------------------------------------------------------------------
__global__ void k_prep(const float* __restrict__ w0ih, const float* __restrict__ w1ih,
                       const float* __restrict__ foW, const float* __restrict__ fiW,
                       unsigned char* ws) {
  unsigned short* wbf = (unsigned short*)(ws + OFF_WBF);
  unsigned int* flags = (unsigned int*)(ws + OFF_FLAG);
  if (blockIdx.x == 0 && threadIdx.x < FL_N) flags[threadIdx.x] = 0u;  // re-zero every launch
  int gid = blockIdx.x * 256 + threadIdx.x;
  if (gid < 7 * WELEM) {
    int which = gid >> 18;
    int idx = gid & (WELEM - 1);
    float v;
    if (which < 4)      v = w0ih[(size_t)which * WELEM + idx];
    else if (which == 4) v = w1ih[idx];
    else if (which == 5) v = foW[idx];
    else                 v = fiW[idx];
    wbf[gid] = f2bf(v);
  }
}

// ---------------------------------------------------------------------------
__global__ __launch_bounds__(256, 1) void k_pipe(
    const float* __restrict__ x,
    const float* __restrict__ w0hh, const float* __restrict__ b0,
    const float* __restrict__ fo_b, const float* __restrict__ fi_b,
    const float* __restrict__ w1hh, const float* __restrict__ b1,
    unsigned char* ws)
{
  __shared__ unsigned short smem[64 * APITCH];   // 33792 B

  float*          xg_ring = (float*)(ws + OFF_XG);
  unsigned short* h_ring  = (unsigned short*)(ws + OFF_H);
  unsigned short* fo_ring = (unsigned short*)(ws + OFF_FO);
  unsigned short* fi_ring = (unsigned short*)(ws + OFF_FI);
  unsigned short* wbf     = (unsigned short*)(ws + OFF_WBF);
  float*          h4_last = (float*)(ws + OFF_H4);
  unsigned int*   flags   = (unsigned int*)(ws + OFF_FLAG);

  const int tid = threadIdx.x;
  const int lane = tid & 63;
  const int wave = tid >> 6;
  const int quad = lane >> 4;
  const int c16 = lane & 15;
  const int bid = blockIdx.x;

  if (bid < NRECB) {
    // ================= recurrent role: layer l, part p =================
    const int l = bid / PREC, p = bid % PREC;
    const int u16 = p * 4 + wave;          // unit tile 0..15
    const int unit = u16 * 16 + c16;       // this lane's hidden unit column
    const float* Whh = (l < 4) ? (w0hh + (size_t)l * NG * H_) : w1hh;

    // B-frags: B[k][n] = Whh[n][k]; lane holds Whh[n_base+c16][kk*32+quad*8+j]
    bf16x8 bfr[4][8];
#pragma unroll
    for (int g = 0; g < 4; ++g) {
      const float* rp = Whh + (size_t)(g * 256 + unit) * H_ + quad * 8;
#pragma unroll
      for (int kk = 0; kk < 8; ++kk) {
        const float* q = rp + kk * 32;
        bf16x8 pk;
#pragma unroll
        for (int jj = 0; jj < 8; ++jj) pk[jj] = (short)f2bf(q[jj]);
        bfr[g][kk] = pk;
      }
    }
    for (int i = tid; i < 16 * APITCH; i += 256) smem[i] = 0;  // h(-1) = 0
    float cst[4] = {0.f, 0.f, 0.f, 0.f};                        // c state
    __syncthreads();

    unsigned int* arr = flags + FL_ARRIVE + l;
    unsigned int* xgf = flags + FL_XGF + l * 16;

    for (int t = 0; t < T_; ++t) {
      if ((t & 7) == 0) {
        if (tid == 0) {
          int tc = t >> 3;
          spin_ge(xgf + (tc & 15), (unsigned)(tc + 1));         // xg chunk ready
          if (l < 4 && tc >= WCH) {                             // h-ring overwrite guard
            unsigned int tgt = (unsigned)(tc - WCH + 1);
            unsigned int* pp = (l < 3) ? (flags + FL_XGP + (l + 1) * GS) : (flags + FL_FOP);
            for (int j2 = 0; j2 < GS; ++j2) spin_ge(pp + j2, tgt);
          }
        }
        __syncthreads();
      }
      // C-init = xg[t]  (layout [slot][n][b] so b is the fast axis -> dwordx4)
      const float* xgs = xg_ring + ((size_t)l * WXG + (size_t)(t & 127)) * (NG * B_);
      f32x4 ac[4];
#pragma unroll
      for (int g = 0; g < 4; ++g)
        ac[g] = *(const f32x4*)(xgs + (size_t)(g * 256 + unit) * B_ + quad * 4);
      // gates += h . Whh^T
#pragma unroll
      for (int kk = 0; kk < 8; ++kk) {
        bf16x8 af = *(const bf16x8*)(&smem[c16 * APITCH + kk * 32 + quad * 8]);
#pragma unroll
        for (int g = 0; g < 4; ++g)
          ac[g] = __builtin_amdgcn_mfma_f32_16x16x32_bf16(af, bfr[g][kk], ac[g], 0, 0, 0);
      }
      // elementwise LSTM cell; lane owns (b=quad*4+r, unit)
      unsigned short* hr = h_ring + ((size_t)l * WH + (size_t)(t & 127)) * (B_ * H_);
#pragma unroll
      for (int r = 0; r < 4; ++r) {
        int b = quad * 4 + r;
        float iv = sigm_f(ac[0][r]);
        float fv = sigm_f(ac[1][r]);
        float gv = tanh_f(ac[2][r]);
        float ov = sigm_f(ac[3][r]);
        cst[r] = fv * cst[r] + iv * gv;
        float hv = ov * tanh_f(cst[r]);
        hr[b * H_ + unit] = f2bf(hv);
        if (l == 4 && t == T_ - 1) h4_last[b * H_ + unit] = hv;
      }
      __syncthreads();                       // all waves done w/ smem + stores drained
      if (tid == 0) {
        __hip_atomic_fetch_add(arr, 1u, __ATOMIC_RELEASE, __HIP_MEMORY_SCOPE_AGENT);
        spin_ge(arr, (unsigned)(PREC * (t + 1)));
      }
      __syncthreads();
      // gather full h[t] (all 4 parts) from ring into LDS for next step's A
      for (int i2 = tid; i2 < 512; i2 += 256) {
        int b = i2 >> 5, u8 = (i2 & 31) * 8;
        *(bf16x8*)(&smem[b * APITCH + u8]) = *(const bf16x8*)(&hr[b * H_ + u8]);
      }
      __syncthreads();
    }
  } else {
    // ================= stream roles =================
    const int s = (bid - NRECB) / GS;   // 0..4 = XG_l, 5 = FO, 6 = FI
    const int j = (bid - NRECB) % GS;
    const bool isXG = (s < 5), isFO = (s == 5), isFI = (s == 6);
    const unsigned short* Bw = wbf + (size_t)(isXG ? s : (isFO ? 5 : 6)) * WELEM;
    const float* bias = isXG ? ((s < 4) ? (b0 + s * NG) : b1) : (isFO ? fo_b : fi_b);
    unsigned int* myprog =
        flags + (isXG ? (FL_XGP + s * GS + j) : (isFO ? (FL_FOP + j) : (FL_FIP + j)));

    for (int tc = j; tc < NCH; tc += GS) {
      if (tid == 0) {
        if (tc >= WCH) {  // output-ring overwrite guard
          unsigned int tgt = (unsigned)(tc - WCH + 1);
          if (isXG) {
            spin_ge(flags + FL_ARRIVE + s, (unsigned)(PREC * CHUNK) * tgt);
          } else if (isFO) {
            for (int j2 = 0; j2 < GS; ++j2) spin_ge(flags + FL_FIP + j2, tgt);
          } else {
            for (int j2 = 0; j2 < GS; ++j2) spin_ge(flags + FL_XGP + 4 * GS + j2, tgt);
          }
        }
        // input readiness
        if (isXG) {
          if (s >= 1 && s <= 3) spin_ge(flags + FL_ARRIVE + (s - 1), (unsigned)(PREC * CHUNK * (tc + 1)));
          else if (s == 4)      spin_ge(flags + FL_FIF + (tc & 15), (unsigned)(tc + 1));
        } else if (isFO) {
          spin_ge(flags + FL_ARRIVE + 3, (unsigned)(PREC * CHUNK * (tc + 1)));
        } else {
          spin_ge(flags + FL_FOF + (tc & 15), (unsigned)(tc + 1));
        }
      }
      __syncthreads();

      if (!isFI) {
        // [128,256] x [256,1024]: 8 M-tiles x 64 N-tiles, K=256
#pragma unroll
        for (int m_blk = 0; m_blk < 2; ++m_blk) {
          __syncthreads();
          { // stage 64 A rows into LDS (bf16)
            int rloc = tid >> 2;
            int k0 = (tid & 3) * 64;
            int row = m_blk * 64 + rloc;
            int tl = row >> 4, b = row & 15;
            int t = tc * CHUNK + tl;
            unsigned short* dst = &smem[rloc * APITCH + k0];
            if (s == 0) {
              const float* src = x + ((size_t)b * T_ + t) * H_ + k0;
#pragma unroll
              for (int i = 0; i < 16; ++i) {
                f32x4 v = *(const f32x4*)(src + i * 4);
                *(unsigned int*)(dst + i * 4)     = (unsigned)f2bf(v[0]) | ((unsigned)f2bf(v[1]) << 16);
                *(unsigned int*)(dst + i * 4 + 2) = (unsigned)f2bf(v[2]) | ((unsigned)f2bf(v[3]) << 16);
              }
            } else {
              const unsigned short* src;
              if (isXG && s <= 3)
                src = h_ring + ((size_t)(s - 1) * WH + (size_t)(t & 127)) * (B_ * H_) + b * H_ + k0;
              else if (isXG)  // s == 4: input is fan-in output
                src = fi_ring + ((size_t)(tc & 15) * 128 + row) * H_ + k0;
              else            // FO: input is h3
                src = h_ring + ((size_t)3 * WH + (size_t)(t & 127)) * (B_ * H_) + b * H_ + k0;
#pragma unroll
              for (int i = 0; i < 8; ++i)
                *(bf16x8*)(dst + i * 8) = *(const bf16x8*)(src + i * 8);
            }
          }
          __syncthreads();
          bf16x8 afr[4][8];
#pragma unroll
          for (int mt = 0; mt < 4; ++mt)
#pragma unroll
            for (int kk = 0; kk < 8; ++kk)
              afr[mt][kk] = *(const bf16x8*)(&smem[(mt * 16 + c16) * APITCH + kk * 32 + quad * 8]);
          for (int nn = 0; nn < 16; ++nn) {
            int n = (wave * 16 + nn) * 16 + c16;
            const unsigned short* bp = Bw + (size_t)n * 256 + quad * 8;
            bf16x8 bfr2[8];
#pragma unroll
            for (int kk = 0; kk < 8; ++kk) bfr2[kk] = *(const bf16x8*)(bp + kk * 32);
            f32x4 ac[4];
#pragma unroll
            for (int mt = 0; mt < 4; ++mt) ac[mt] = (f32x4){0.f, 0.f, 0.f, 0.f};
#pragma unroll
            for (int kk = 0; kk < 8; ++kk)
#pragma unroll
              for (int mt = 0; mt < 4; ++mt)
                ac[mt] = __builtin_amdgcn_mfma_f32_16x16x32_bf16(afr[mt][kk], bfr2[kk], ac[mt], 0, 0, 0);
            float bn = bias[n];
            if (isXG) {
              float* xgbase = xg_ring + (size_t)s * WXG * (NG * B_);
#pragma unroll
              for (int mt = 0; mt < 4; ++mt) {
                int t = tc * CHUNK + m_blk * 4 + mt;
                float* op = xgbase + (size_t)(t & 127) * (NG * B_) + (size_t)n * B_ + quad * 4;
#pragma unroll
                for (int r = 0; r < 4; ++r) op[r] = ac[mt][r] + bn;
              }
            } else {  // FO: bias + LeakyReLU(0.2) -> bf16 ring
#pragma unroll
              for (int mt = 0; mt < 4; ++mt) {
                int row = m_blk * 64 + mt * 16 + quad * 4;
#pragma unroll
                for (int r = 0; r < 4; ++r) {
                  float v = ac[mt][r] + bn;
                  v = v >= 0.f ? v : 0.2f * v;
                  fo_ring[((size_t)(tc & 15) * 128 + row + r) * F_ + n] = f2bf(v);
                }
              }
            }
          }
        }
      } else {
        // FI: [128,1024] x [1024,256], K in 4 slices, 16 N-tiles (4/wave)
        f32x4 acc[2][4][4];
#pragma unroll
        for (int a1 = 0; a1 < 2; ++a1)
#pragma unroll
          for (int a2 = 0; a2 < 4; ++a2)
#pragma unroll
            for (int a3 = 0; a3 < 4; ++a3) acc[a1][a2][a3] = (f32x4){0.f, 0.f, 0.f, 0.f};
#pragma unroll
        for (int ks = 0; ks < 4; ++ks) {
#pragma unroll
          for (int m_blk = 0; m_blk < 2; ++m_blk) {
            __syncthreads();
            {
              int rloc = tid >> 2;
              int k0 = (tid & 3) * 64;
              int row = m_blk * 64 + rloc;
              const unsigned short* src =
                  fo_ring + ((size_t)(tc & 15) * 128 + row) * F_ + ks * 256 + k0;
              unsigned short* dst = &smem[rloc * APITCH + k0];
#pragma unroll
              for (int i = 0; i < 8; ++i)
                *(bf16x8*)(dst + i * 8) = *(const bf16x8*)(src + i * 8);
            }
            __syncthreads();
            bf16x8 afr[4][8];
#pragma unroll
            for (int mt = 0; mt < 4; ++mt)
#pragma unroll
              for (int kk = 0; kk < 8; ++kk)
                afr[mt][kk] = *(const bf16x8*)(&smem[(mt * 16 + c16) * APITCH + kk * 32 + quad * 8]);
#pragma unroll
            for (int nn = 0; nn < 4; ++nn) {
              int n = (wave * 4 + nn) * 16 + c16;
              const unsigned short* bp = Bw + (size_t)n * 1024 + ks * 256 + quad * 8;
              bf16x8 bfr2[8];
#pragma unroll
              for (int kk = 0; kk < 8; ++kk) bfr2[kk] = *(const bf16x8*)(bp + kk * 32);
#pragma unroll
              for (int kk = 0; kk < 8; ++kk)
#pragma unroll
                for (int mt = 0; mt < 4; ++mt)
                  acc[m_blk][nn][mt] =
                      __builtin_amdgcn_mfma_f32_16x16x32_bf16(afr[mt][kk], bfr2[kk], acc[m_blk][nn][mt], 0, 0, 0);
            }
          }
        }
#pragma unroll
        for (int m_blk = 0; m_blk < 2; ++m_blk)
#pragma unroll
          for (int nn = 0; nn < 4; ++nn) {
            int n = (wave * 4 + nn) * 16 + c16;
            float bn = bias[n];
#pragma unroll
            for (int mt = 0; mt < 4; ++mt) {
              int row = m_blk * 64 + mt * 16 + quad * 4;
#pragma unroll
              for (int r = 0; r < 4; ++r)
                fi_ring[((size_t)(tc & 15) * 128 + row + r) * H_ + n] = f2bf(acc[m_blk][nn][mt][r] + bn);
            }
          }
      }
      __syncthreads();
      if (tid == 0) {
        unsigned int* fl = isXG ? (flags + FL_XGF + s * 16 + (tc & 15))
                                : (isFO ? (flags + FL_FOF + (tc & 15)) : (flags + FL_FIF + (tc & 15)));
        __hip_atomic_store(fl, (unsigned)(tc + 1), __ATOMIC_RELEASE, __HIP_MEMORY_SCOPE_AGENT);
        __hip_atomic_store(myprog, (unsigned)(tc + 1), __ATOMIC_RELAXED, __HIP_MEMORY_SCOPE_AGENT);
      }
    }
  }
}

// ---------------------------------------------------------------------------
__global__ void k_head(const float* __restrict__ hW, const float* __restrict__ hb,
                       unsigned char* ws, float* __restrict__ out) {
  __shared__ float red[256];
  const float* h4 = (const float*)(ws + OFF_H4);
  int tid = threadIdx.x;
  int b = tid >> 4, k0 = tid & 15;
  float sum = 0.f;
  for (int k = k0; k < H_; k += 16) sum += h4[b * H_ + k] * hW[k];
  red[tid] = sum;
  __syncthreads();
  if (tid < B_) {
    float z = hb[0];
    for (int i = 0; i < 16; ++i) z += red[tid * 16 + i];
    out[tid] = 1.0f / (1.0f + __expf(-z));
  }
}

// ---------------------------------------------------------------------------
extern "C" void kernel_launch(void* const* d_in, const int* in_sizes, int n_in,
                              void* d_out, int out_size, void* d_ws, size_t ws_size,
                              hipStream_t stream) {
  const float* x    = (const float*)d_in[0];
  const float* w0ih = (const float*)d_in[1];
  const float* w0hh = (const float*)d_in[2];
  const float* b0   = (const float*)d_in[3];
  const float* foW  = (const float*)d_in[4];
  const float* fob  = (const float*)d_in[5];
  const float* fiW  = (const float*)d_in[6];
  const float* fib  = (const float*)d_in[7];
  const float* w1ih = (const float*)d_in[8];
  const float* w1hh = (const float*)d_in[9];
  const float* b1   = (const float*)d_in[10];
  const float* hW   = (const float*)d_in[11];
  const float* hb   = (const float*)d_in[12];
  unsigned char* ws = (unsigned char*)d_ws;
  (void)in_sizes; (void)n_in; (void)out_size; (void)ws_size;

  hipLaunchKernelGGL(k_prep, dim3(7168), dim3(256), 0, stream, w0ih, w1ih, foW, fiW, ws);
  hipLaunchKernelGGL(k_pipe, dim3(NBLK), dim3(256), 0, stream,
                     x, w0hh, b0, fob, fib, w1hh, b1, ws);
  hipLaunchKernelGGL(k_head, dim3(1), dim3(256), 0, stream, hW, hb, ws, (float*)d_out);
}

// Round 2
// 7747.729 us; speedup vs baseline: 1.3076x; 1.3076x over previous
//
#include <hip/hip_runtime.h>
#include <stdint.h>

// ---------------------------------------------------------------------------
// 4-layer stacked LSTM -> fanout/LeakyReLU/fanin -> LSTM -> head(sigmoid)
// as one persistent producer/consumer pipeline.
//
// R2 change vs R1: all cross-block ring traffic uses RELAXED agent-scope
// atomics (coherent per-access at LLC). No acquire/release fences in the
// steady state -> no per-step buffer_wbl2 / buffer_inv (the R1 tax).
//
// k_pipe blocks (56 x 256 threads):
//   0..19  REC   (5 layers x 4 blocks) - serial recurrence, Whh in VGPRs
//   20..39 XG0-4 (4 blocks each)       - xg = h_{l-1}.Wih^T + b, 8-step chunks
//   40..47 FO    (8 blocks)            - fanout + LeakyReLU
//   48..55 FI    (8 blocks)            - fanin
// ---------------------------------------------------------------------------

#define B_ 16
#define T_ 2048
#define H_ 256
#define NG 1024
#define F_ 1024
#define CHUNK 8
#define NCH 256            // T_/CHUNK
#define WH 128             // h ring depth (steps)
#define WXG 128            // xg ring depth (steps)
#define WCH 16             // chunk-granular ring depth
#define PREC 4
#define NRECB 20
#define NBLK 56
#define APITCH 264         // LDS row pitch (bf16 elems)
#define WELEM 262144       // 1024*256

typedef __attribute__((ext_vector_type(4))) float f32x4;
typedef __attribute__((ext_vector_type(8))) short bf16x8;
typedef unsigned long long ull;

// ---- workspace layout ----
#define OFF_XG   0ul
#define SZ_XG    (5ul*WXG*NG*B_*4ul)                 // f32 [5][128][1024][16]
#define OFF_H    (OFF_XG + SZ_XG)
#define SZ_H     (5ul*WH*B_*H_*2ul)                  // bf16 [5][128][16][256]
#define OFF_FO   (OFF_H + SZ_H)
#define SZ_FO    ((unsigned long)WCH*128ul*F_*2ul)   // bf16 [16][128][1024]
#define OFF_FI   (OFF_FO + SZ_FO)
#define SZ_FI    ((unsigned long)WCH*128ul*H_*2ul)   // bf16 [16][128][256]
#define OFF_WBF  (OFF_FI + SZ_FI)
#define SZ_WBF   (7ul*WELEM*2ul)
#define OFF_H4   (OFF_WBF + SZ_WBF)
#define OFF_FLAG (OFF_H4 + 16384ul + 256ul)

// flag word indices (arrival counters padded to 64B lines)
#define FL_ARR(l)  ((l)*16)
#define FL_XGF(s)  (80 + (s)*16)     // [16] slots per stage, value tc+1
#define FL_FOF     160               // [16]
#define FL_FIF     176               // [16]
#define FL_XGP(s)  (192 + (s)*4)     // [5][4] producer progress (chunks)
#define FL_FOP     212               // [8]
#define FL_FIP     220               // [8]
#define FL_N       256

__device__ __forceinline__ unsigned short f2bf(float f) {
  unsigned int u = __float_as_uint(f);
  u = u + 0x7fffu + ((u >> 16) & 1u);
  return (unsigned short)(u >> 16);
}
__device__ __forceinline__ float sigm_f(float x) { return 1.0f / (1.0f + __expf(-x)); }
__device__ __forceinline__ float tanh_f(float x) {
  float e = __expf(-2.0f * fabsf(x));
  float r = (1.0f - e) / (1.0f + e);
  return x >= 0.0f ? r : -r;
}
__device__ __forceinline__ unsigned ld32(const void* p) {
  return __hip_atomic_load((const unsigned*)p, __ATOMIC_RELAXED, __HIP_MEMORY_SCOPE_AGENT);
}
__device__ __forceinline__ void st32(void* p, unsigned v) {
  __hip_atomic_store((unsigned*)p, v, __ATOMIC_RELAXED, __HIP_MEMORY_SCOPE_AGENT);
}
__device__ __forceinline__ ull ld64(const void* p) {
  return __hip_atomic_load((const ull*)p, __ATOMIC_RELAXED, __HIP_MEMORY_SCOPE_AGENT);
}
__device__ __forceinline__ void st64(void* p, ull v) {
  __hip_atomic_store((ull*)p, v, __ATOMIC_RELAXED, __HIP_MEMORY_SCOPE_AGENT);
}
// relaxed spin (bounded: a protocol bug -> wrong output, not a hang)
__device__ __forceinline__ void spin_ge(unsigned int* p, unsigned int tgt) {
  int n = 0;
  while (ld32(p) < tgt) {
    __builtin_amdgcn_s_sleep(1);
    if (++n > 20000000) break;
  }
}

// ---------------------------------------------------------------------------
__global__ void k_prep(const float* __restrict__ w0ih, const float* __restrict__ w1ih,
                       const float* __restrict__ foW, const float* __restrict__ fiW,
                       unsigned char* ws) {
  unsigned short* wbf = (unsigned short*)(ws + OFF_WBF);
  unsigned int* flags = (unsigned int*)(ws + OFF_FLAG);
  if (blockIdx.x == 0 && threadIdx.x < FL_N) flags[threadIdx.x] = 0u;
  int gid = blockIdx.x * 256 + threadIdx.x;
  if (gid < 7 * WELEM) {
    int which = gid >> 18;
    int idx = gid & (WELEM - 1);
    float v;
    if (which < 4)       v = w0ih[(size_t)which * WELEM + idx];
    else if (which == 4) v = w1ih[idx];
    else if (which == 5) v = foW[idx];
    else                 v = fiW[idx];
    wbf[gid] = f2bf(v);
  }
}

// ---------------------------------------------------------------------------
__global__ __launch_bounds__(256, 1) void k_pipe(
    const float* __restrict__ x,
    const float* __restrict__ w0hh, const float* __restrict__ b0,
    const float* __restrict__ fo_b, const float* __restrict__ fi_b,
    const float* __restrict__ w1hh, const float* __restrict__ b1,
    unsigned char* ws)
{
  __shared__ unsigned short smem[64 * APITCH];   // 33792 B (REC uses first 2*16 rows)

  float*          xg_ring = (float*)(ws + OFF_XG);
  unsigned short* h_ring  = (unsigned short*)(ws + OFF_H);
  unsigned short* fo_ring = (unsigned short*)(ws + OFF_FO);
  unsigned short* fi_ring = (unsigned short*)(ws + OFF_FI);
  unsigned short* wbf     = (unsigned short*)(ws + OFF_WBF);
  float*          h4_last = (float*)(ws + OFF_H4);
  unsigned int*   flags   = (unsigned int*)(ws + OFF_FLAG);

  const int tid = threadIdx.x;
  const int lane = tid & 63;
  const int wave = tid >> 6;
  const int quad = lane >> 4;
  const int c16 = lane & 15;
  const int bid = blockIdx.x;

  if (bid < NRECB) {
    // ================= recurrent role: layer l, part p =================
    const int l = bid / PREC, p = bid % PREC;
    const int u16 = p * 4 + wave;
    const int unit = u16 * 16 + c16;
    const float* Whh = (l < 4) ? (w0hh + (size_t)l * NG * H_) : w1hh;

    bf16x8 bfr[4][8];   // B-frags: Whh[n][k], n = gate*256+unit
#pragma unroll
    for (int g = 0; g < 4; ++g) {
      const float* rp = Whh + (size_t)(g * 256 + unit) * H_ + quad * 8;
#pragma unroll
      for (int kk = 0; kk < 8; ++kk) {
        const float* q = rp + kk * 32;
        bf16x8 pk;
#pragma unroll
        for (int jj = 0; jj < 8; ++jj) pk[jj] = (short)f2bf(q[jj]);
        bfr[g][kk] = pk;
      }
    }
    for (int i = tid; i < 2 * 16 * APITCH; i += 256) smem[i] = 0;  // h(-1)=0
    float cst[4] = {0.f, 0.f, 0.f, 0.f};
    __syncthreads();

    unsigned int* arr = flags + FL_ARR(l);
    unsigned int* xgf = flags + FL_XGF(l);

    for (int t = 0; t < T_; ++t) {
      if ((t & 7) == 0) {
        if (tid == 0) {
          int tc = t >> 3;
          spin_ge(xgf + (tc & 15), (unsigned)(tc + 1));   // xg chunk ready
          if (l < 4 && tc >= WCH) {                        // h-ring overwrite guard
            unsigned int tgt = (unsigned)(tc - WCH + 1);
            if (l < 3) { unsigned int* pp = flags + FL_XGP(l + 1);
                         for (int j2 = 0; j2 < 4; ++j2) spin_ge(pp + j2, tgt); }
            else       { unsigned int* pp = flags + FL_FOP;
                         for (int j2 = 0; j2 < 8; ++j2) spin_ge(pp + j2, tgt); }
          }
        }
        __syncthreads();
      }
      // xg loads issued first (latency hides under MFMA; added post-MFMA)
      const ull* xg8 = (const ull*)(xg_ring + ((size_t)l * WXG + (size_t)(t & 127)) * (NG * B_));
      union { ull u; float f[2]; } xa[4][2];
#pragma unroll
      for (int g = 0; g < 4; ++g) {
        size_t n8 = (size_t)(g * 256 + unit) * 8 + quad * 2;
        xa[g][0].u = ld64(xg8 + n8);
        xa[g][1].u = ld64(xg8 + n8 + 1);
      }
      // gates = h . Whh^T  (C starts at 0)
      const int cb = t & 1, nb = cb ^ 1;
      f32x4 ac[4];
#pragma unroll
      for (int g = 0; g < 4; ++g) ac[g] = (f32x4){0.f, 0.f, 0.f, 0.f};
#pragma unroll
      for (int kk = 0; kk < 8; ++kk) {
        bf16x8 af = *(const bf16x8*)(&smem[cb * 16 * APITCH + c16 * APITCH + kk * 32 + quad * 8]);
#pragma unroll
        for (int g = 0; g < 4; ++g)
          ac[g] = __builtin_amdgcn_mfma_f32_16x16x32_bf16(af, bfr[g][kk], ac[g], 0, 0, 0);
      }
      // elementwise cell; lane owns (b=quad*4+r, unit)
      unsigned short* hrw = h_ring + ((size_t)l * WH + (size_t)(t & 127)) * (B_ * H_);
      float hv[4];
#pragma unroll
      for (int r = 0; r < 4; ++r) {
        float iv = sigm_f(ac[0][r] + xa[0][r >> 1].f[r & 1]);
        float fv = sigm_f(ac[1][r] + xa[1][r >> 1].f[r & 1]);
        float gv = tanh_f(ac[2][r] + xa[2][r >> 1].f[r & 1]);
        float ov = sigm_f(ac[3][r] + xa[3][r >> 1].f[r & 1]);
        cst[r] = fv * cst[r] + iv * gv;
        hv[r] = ov * tanh_f(cst[r]);
        if (l == 4 && t == T_ - 1) h4_last[(quad * 4 + r) * H_ + unit] = hv[r];
      }
      // pack bf16 pairs via shfl; even lanes store (own LDS + ring atomic)
#pragma unroll
      for (int r = 0; r < 4; ++r) {
        float oth = __shfl_xor(hv[r], 1, 64);
        if ((lane & 1) == 0) {
          unsigned pk = (unsigned)f2bf(hv[r]) | ((unsigned)f2bf(oth) << 16);
          int b = quad * 4 + r;
          *(unsigned*)&smem[nb * 16 * APITCH + b * APITCH + unit] = pk;   // LDS
          st32(hrw + (size_t)b * H_ + unit, pk);                          // ring
        }
      }
      __syncthreads();   // compiler drains vmcnt before s_barrier -> stores @ LLC
      if (tid == 0) {
        __hip_atomic_fetch_add(arr, 1u, __ATOMIC_RELAXED, __HIP_MEMORY_SCOPE_AGENT);
        spin_ge(arr, (unsigned)(PREC * (t + 1)));
      }
      __syncthreads();
      // gather 3 foreign quarters: thread -> (b=tid>>4, k=tid&15), 8B each
      {
        const ull* hr8 = (const ull*)hrw;
        int b = tid >> 4, k = tid & 15;
#pragma unroll
        for (int fp = 0; fp < 3; ++fp) {
          int p2 = fp + (fp >= p ? 1 : 0);
          ull v = ld64(hr8 + (size_t)b * 64 + p2 * 16 + k);
          *(ull*)&smem[nb * 16 * APITCH + b * APITCH + p2 * 64 + k * 4] = v;
        }
      }
      __syncthreads();
    }
  } else {
    // ================= stream roles =================
    int sb = bid - NRECB, s, j, GSS;
    if (sb < 20)      { s = sb >> 2; j = sb & 3;  GSS = 4; }
    else if (sb < 28) { s = 5;       j = sb - 20; GSS = 8; }
    else              { s = 6;       j = sb - 28; GSS = 8; }
    const bool isXG = (s < 5), isFO = (s == 5), isFI = (s == 6);
    const unsigned short* Bw = wbf + (size_t)(isXG ? s : (isFO ? 5 : 6)) * WELEM;
    const float* bias = isXG ? ((s < 4) ? (b0 + s * NG) : b1) : (isFO ? fo_b : fi_b);
    unsigned int* myprog =
        flags + (isXG ? (FL_XGP(s) + j) : (isFO ? (FL_FOP + j) : (FL_FIP + j)));

    for (int tc = j; tc < NCH; tc += GSS) {
      if (tid == 0) {
        if (tc >= WCH) {  // output-ring overwrite guard
          unsigned int tgt = (unsigned)(tc - WCH + 1);
          if (isXG) {
            spin_ge(flags + FL_ARR(s), (unsigned)(PREC * CHUNK) * tgt);
          } else if (isFO) {
            for (int j2 = 0; j2 < 8; ++j2) spin_ge(flags + FL_FIP + j2, tgt);
          } else {
            for (int j2 = 0; j2 < 4; ++j2) spin_ge(flags + FL_XGP(4) + j2, tgt);
          }
        }
        // input readiness
        if (isXG) {
          if (s >= 1 && s <= 3) spin_ge(flags + FL_ARR(s - 1), (unsigned)(PREC * CHUNK * (tc + 1)));
          else if (s == 4)      spin_ge(flags + FL_FIF + (tc & 15), (unsigned)(tc + 1));
        } else if (isFO) {
          spin_ge(flags + FL_ARR(3), (unsigned)(PREC * CHUNK * (tc + 1)));
        } else {
          spin_ge(flags + FL_FOF + (tc & 15), (unsigned)(tc + 1));
        }
      }
      __syncthreads();

      if (!isFI) {
        // [128,256] x [256,1024]
#pragma unroll
        for (int m_blk = 0; m_blk < 2; ++m_blk) {
          __syncthreads();
          { // stage 64 A rows into LDS (bf16)
            int rloc = tid >> 2;
            int k0 = (tid & 3) * 64;
            int row = m_blk * 64 + rloc;
            int tl = row >> 4, b = row & 15;
            int t = tc * CHUNK + tl;
            unsigned short* dst = &smem[rloc * APITCH + k0];
            if (s == 0) {
              const float* src = x + ((size_t)b * T_ + t) * H_ + k0;
#pragma unroll
              for (int i = 0; i < 16; ++i) {
                f32x4 v = *(const f32x4*)(src + i * 4);
                *(unsigned*)(dst + i * 4)     = (unsigned)f2bf(v[0]) | ((unsigned)f2bf(v[1]) << 16);
                *(unsigned*)(dst + i * 4 + 2) = (unsigned)f2bf(v[2]) | ((unsigned)f2bf(v[3]) << 16);
              }
            } else {
              const unsigned short* src;
              if (isXG && s <= 3)
                src = h_ring + ((size_t)(s - 1) * WH + (size_t)(t & 127)) * (B_ * H_) + b * H_ + k0;
              else if (isXG)  // s==4: fan-in output
                src = fi_ring + ((size_t)(tc & 15) * 128 + row) * H_ + k0;
              else            // FO: h3
                src = h_ring + ((size_t)3 * WH + (size_t)(t & 127)) * (B_ * H_) + b * H_ + k0;
#pragma unroll
              for (int i = 0; i < 16; ++i)
                *(ull*)(dst + i * 4) = ld64((const ull*)src + i);
            }
          }
          __syncthreads();
          bf16x8 afr[4][8];
#pragma unroll
          for (int mt = 0; mt < 4; ++mt)
#pragma unroll
            for (int kk = 0; kk < 8; ++kk)
              afr[mt][kk] = *(const bf16x8*)(&smem[(mt * 16 + c16) * APITCH + kk * 32 + quad * 8]);
          for (int nn = 0; nn < 16; ++nn) {
            int n = (wave * 16 + nn) * 16 + c16;
            const unsigned short* bp = Bw + (size_t)n * 256 + quad * 8;
            bf16x8 bfr2[8];
#pragma unroll
            for (int kk = 0; kk < 8; ++kk) bfr2[kk] = *(const bf16x8*)(bp + kk * 32);
            f32x4 ac[4];
#pragma unroll
            for (int mt = 0; mt < 4; ++mt) ac[mt] = (f32x4){0.f, 0.f, 0.f, 0.f};
#pragma unroll
            for (int kk = 0; kk < 8; ++kk)
#pragma unroll
              for (int mt = 0; mt < 4; ++mt)
                ac[mt] = __builtin_amdgcn_mfma_f32_16x16x32_bf16(afr[mt][kk], bfr2[kk], ac[mt], 0, 0, 0);
            float bn = bias[n];
            if (isXG) {
              ull* xg8 = (ull*)(xg_ring + (size_t)s * WXG * (NG * B_));
#pragma unroll
              for (int mt = 0; mt < 4; ++mt) {
                int t = tc * CHUNK + m_blk * 4 + mt;
                size_t bi = ((size_t)(t & 127) * (NG * B_) + (size_t)n * B_ + quad * 4) >> 1;
                union { ull u; float f[2]; } u0, u1;
                u0.f[0] = ac[mt][0] + bn; u0.f[1] = ac[mt][1] + bn;
                u1.f[0] = ac[mt][2] + bn; u1.f[1] = ac[mt][3] + bn;
                st64(xg8 + bi, u0.u);
                st64(xg8 + bi + 1, u1.u);
              }
            } else {  // FO: bias + LeakyReLU -> bf16 ring (shfl-packed pairs)
#pragma unroll
              for (int mt = 0; mt < 4; ++mt) {
                int row = m_blk * 64 + mt * 16 + quad * 4;
#pragma unroll
                for (int r = 0; r < 4; ++r) {
                  float v = ac[mt][r] + bn;
                  v = v >= 0.f ? v : 0.2f * v;
                  float oth = __shfl_xor(v, 1, 64);
                  if ((lane & 1) == 0) {
                    unsigned pk = (unsigned)f2bf(v) | ((unsigned)f2bf(oth) << 16);
                    st32(fo_ring + ((size_t)(tc & 15) * 128 + row + r) * F_ + n, pk);
                  }
                }
              }
            }
          }
        }
      } else {
        // FI: [128,1024] x [1024,256]
        f32x4 acc[2][4][4];
#pragma unroll
        for (int a1 = 0; a1 < 2; ++a1)
#pragma unroll
          for (int a2 = 0; a2 < 4; ++a2)
#pragma unroll
            for (int a3 = 0; a3 < 4; ++a3) acc[a1][a2][a3] = (f32x4){0.f, 0.f, 0.f, 0.f};
#pragma unroll
        for (int ks = 0; ks < 4; ++ks) {
#pragma unroll
          for (int m_blk = 0; m_blk < 2; ++m_blk) {
            __syncthreads();
            {
              int rloc = tid >> 2;
              int k0 = (tid & 3) * 64;
              int row = m_blk * 64 + rloc;
              const unsigned short* src =
                  fo_ring + ((size_t)(tc & 15) * 128 + row) * F_ + ks * 256 + k0;
              unsigned short* dst = &smem[rloc * APITCH + k0];
#pragma unroll
              for (int i = 0; i < 16; ++i)
                *(ull*)(dst + i * 4) = ld64((const ull*)src + i);
            }
            __syncthreads();
            bf16x8 afr[4][8];
#pragma unroll
            for (int mt = 0; mt < 4; ++mt)
#pragma unroll
              for (int kk = 0; kk < 8; ++kk)
                afr[mt][kk] = *(const bf16x8*)(&smem[(mt * 16 + c16) * APITCH + kk * 32 + quad * 8]);
#pragma unroll
            for (int nn = 0; nn < 4; ++nn) {
              int n = (wave * 4 + nn) * 16 + c16;
              const unsigned short* bp = Bw + (size_t)n * 1024 + ks * 256 + quad * 8;
              bf16x8 bfr2[8];
#pragma unroll
              for (int kk = 0; kk < 8; ++kk) bfr2[kk] = *(const bf16x8*)(bp + kk * 32);
#pragma unroll
              for (int kk = 0; kk < 8; ++kk)
#pragma unroll
                for (int mt = 0; mt < 4; ++mt)
                  acc[m_blk][nn][mt] =
                      __builtin_amdgcn_mfma_f32_16x16x32_bf16(afr[mt][kk], bfr2[kk], acc[m_blk][nn][mt], 0, 0, 0);
            }
          }
        }
#pragma unroll
        for (int m_blk = 0; m_blk < 2; ++m_blk)
#pragma unroll
          for (int nn = 0; nn < 4; ++nn) {
            int n = (wave * 4 + nn) * 16 + c16;
            float bn = bias[n];
#pragma unroll
            for (int mt = 0; mt < 4; ++mt) {
              int row = m_blk * 64 + mt * 16 + quad * 4;
#pragma unroll
              for (int r = 0; r < 4; ++r) {
                float v = acc[m_blk][nn][mt][r] + bn;
                float oth = __shfl_xor(v, 1, 64);
                if ((lane & 1) == 0) {
                  unsigned pk = (unsigned)f2bf(v) | ((unsigned)f2bf(oth) << 16);
                  st32(fi_ring + ((size_t)(tc & 15) * 128 + row + r) * H_ + n, pk);
                }
              }
            }
          }
      }
      __syncthreads();   // drains all waves' ring stores before flag publish
      if (tid == 0) {
        unsigned int* fl = isXG ? (flags + FL_XGF(s) + (tc & 15))
                                : (isFO ? (flags + FL_FOF + (tc & 15)) : (flags + FL_FIF + (tc & 15)));
        st32(fl, (unsigned)(tc + 1));
        st32(myprog, (unsigned)(tc + 1));
      }
    }
  }
}

// ---------------------------------------------------------------------------
__global__ void k_head(const float* __restrict__ hW, const float* __restrict__ hb,
                       unsigned char* ws, float* __restrict__ out) {
  __shared__ float red[256];
  const float* h4 = (const float*)(ws + OFF_H4);
  int tid = threadIdx.x;
  int b = tid >> 4, k0 = tid & 15;
  float sum = 0.f;
  for (int k = k0; k < H_; k += 16) sum += h4[b * H_ + k] * hW[k];
  red[tid] = sum;
  __syncthreads();
  if (tid < B_) {
    float z = hb[0];
    for (int i = 0; i < 16; ++i) z += red[tid * 16 + i];
    out[tid] = 1.0f / (1.0f + __expf(-z));
  }
}

// ---------------------------------------------------------------------------
extern "C" void kernel_launch(void* const* d_in, const int* in_sizes, int n_in,
                              void* d_out, int out_size, void* d_ws, size_t ws_size,
                              hipStream_t stream) {
  const float* x    = (const float*)d_in[0];
  const float* w0ih = (const float*)d_in[1];
  const float* w0hh = (const float*)d_in[2];
  const float* b0   = (const float*)d_in[3];
  const float* foW  = (const float*)d_in[4];
  const float* fob  = (const float*)d_in[5];
  const float* fiW  = (const float*)d_in[6];
  const float* fib  = (const float*)d_in[7];
  const float* w1ih = (const float*)d_in[8];
  const float* w1hh = (const float*)d_in[9];
  const float* b1   = (const float*)d_in[10];
  const float* hW   = (const float*)d_in[11];
  const float* hb   = (const float*)d_in[12];
  unsigned char* ws = (unsigned char*)d_ws;
  (void)in_sizes; (void)n_in; (void)out_size; (void)ws_size;

  hipLaunchKernelGGL(k_prep, dim3(7168), dim3(256), 0, stream, w0ih, w1ih, foW, fiW, ws);
  hipLaunchKernelGGL(k_pipe, dim3(NBLK), dim3(256), 0, stream,
                     x, w0hh, b0, fob, fib, w1hh, b1, ws);
  hipLaunchKernelGGL(k_head, dim3(1), dim3(256), 0, stream, hW, hb, ws, (float*)d_out);
}